// Round 8
// baseline (238.862 us; speedup 1.0000x reference)
//
#include <hip/hip_runtime.h>
#include <hip/hip_bf16.h>

// B=4, L=4096, D=1024; M = B*L = 16384. ALL I/O IS FP32.
// Live path: h = (x@Wp[:,0:D]) * sigmoid(x@Wp[:,2D:3D]); out = h@W_out + b_out
// Internals: bf16 MFMA, fp32 accumulation.
//
// Round-8:
//  - gemm1: EXACT round-4 kernel (best measured: 73.7 us, 935 TF).
//  - gemm2: STRUCTURAL CLONE of that gemm1 (the only template measured fast):
//    BM=256, BN=256 as 4x64-col j-panels (replacing gemm1's Bg/Bo dual
//    panels), 8 waves (2M x 4N), BK=64, 128 KiB LDS, same 2-phase K-tile,
//    same region/stage/vmcnt(4) bookkeeping. Per-wave per-tile profile is
//    IDENTICAL to gemm1: 24 ds_read_b128 + 12 staged loads + 64 MFMA.
//    Grid: big-ws 256 blocks = exactly one full-machine round (gemm1 does
//    two rounds in 73.7 us -> predict ~37-45 us); small-ws 2 x 128.
//    Rounds 2-7 gemm2 variants (~105-115 us total, never in top-5) all
//    deviated from the proven structure; this one doesn't.
//
// 2-phase K-tile kt (buf b=kt&1, nb=b^1), 1 barrier per phase:
//   p0: read A-h0(8) + ALL B(8); stage kt+1 {A2,A3,B2,B3}->nb; MFMA h0 (32)
//   p1: read A-h1(8);            stage kt+2 {A0,A1,B0,B1}->b;  MFMA h1 (32)
//   vmcnt(4) at p1-end: drains kt+1's 4, leaves kt+2's 4 in flight.
//   stage-safety: every staged region's last ds_read completed >= 1 barrier
//   earlier (reads drain via pre-MFMA lgkmcnt(0); stage issues after the
//   phase-end barrier that follows).
// T2 LDS XOR swizzle (slot^=row&7 on 128B rows; linear LDS dest +
// inverse-swizzled global source), T5 setprio, T1 XCD block swizzle.
//
// Memory plan (ws_size-adaptive, branch constant across calls => graph-safe):
//   ws shorts [0,3M)   : WgT | WoT | WoutT bf16 panels (6 MB)
//   BIG ws (>=38 MB)   : H (16M shorts) entirely at ws+3M; single gemm2 launch.
//   SMALL ws           : H rows 0..8191 -> d_out shorts [16M,24M);
//                        H rows 8192..  -> ws+3M; two sequential gemm2 halves.
//   d_out shorts [0,16M): Xbf16 during phases 1-3, then fp32 out rows 0..8191.

#define MTOT 16384
#define DM   1024
#define MEG  (1024 * 1024)

typedef __bf16 bf16x8 __attribute__((ext_vector_type(8)));
typedef float  f32x4  __attribute__((ext_vector_type(4)));

#define AS1 __attribute__((address_space(1)))
#define AS3 __attribute__((address_space(3)))

static __device__ __forceinline__ void async_load16(const void* g, void* l) {
    __builtin_amdgcn_global_load_lds((const AS1 void*)g, (AS3 void*)l, 16, 0, 0);
}

static __device__ __forceinline__ unsigned short f2bf(float f) {
    __hip_bfloat16 h = __float2bfloat16(f);
    return *(unsigned short*)&h;
}

// ---------------- x (fp32) -> Xbf16 ------------------------------------------
__global__ __launch_bounds__(256)
void conv_x(const float* __restrict__ x, unsigned short* __restrict__ dst) {
    const size_t i = ((size_t)blockIdx.x * 256 + threadIdx.x) * 8;
    const f32x4 a = *(const f32x4*)(x + i);
    const f32x4 b = *(const f32x4*)(x + i + 4);
    __align__(16) unsigned short o[8];
    o[0] = f2bf(a[0]); o[1] = f2bf(a[1]); o[2] = f2bf(a[2]); o[3] = f2bf(a[3]);
    o[4] = f2bf(b[0]); o[5] = f2bf(b[1]); o[6] = f2bf(b[2]); o[7] = f2bf(b[3]);
    *(uint4*)(dst + i) = *(const uint4*)o;
}

// -------- weight transpose+convert: dst[n][k] = bf16(src[k][coff+n]) ---------
__global__ void transpose_w(const float* __restrict__ Wproj, const float* __restrict__ Wout,
                            unsigned short* __restrict__ dst0) {
    __shared__ unsigned short t[32][33];
    const int z = blockIdx.z;
    const float* src;
    unsigned short* dst;
    int ld, coff;
    if (z == 0)      { src = Wproj; ld = 3072; coff = 0;    dst = dst0; }
    else if (z == 1) { src = Wproj; ld = 3072; coff = 2048; dst = dst0 + MEG; }
    else             { src = Wout;  ld = 1024; coff = 0;    dst = dst0 + 2 * MEG; }
    const int k0 = blockIdx.x * 32;
    const int n0 = blockIdx.y * 32;
    const int tx = threadIdx.x, ty = threadIdx.y;
    for (int i = ty; i < 32; i += 8)
        t[i][tx] = f2bf(src[(size_t)(k0 + i) * ld + coff + n0 + tx]);
    __syncthreads();
    for (int i = ty; i < 32; i += 8)
        dst[(size_t)(n0 + i) * DM + k0 + tx] = t[tx][i];
}

// ---------- GEMM1 fused: H = (X@Wg + bg) * sigmoid(X@Wo + bo) ---------------
// EXACT round-4 kernel. 512 thr / 8 waves (2M x 4N); BM=256, BN=128(x2 mats).
__global__ __launch_bounds__(512)
void gemm1_fused(const unsigned short* __restrict__ X,
                 const unsigned short* __restrict__ WgT,
                 const unsigned short* __restrict__ WoT,
                 const float* __restrict__ bproj,
                 unsigned short* __restrict__ Hlo,
                 unsigned short* __restrict__ Hhi) {
    __shared__ __align__(16) unsigned short sA[2][256 * 64];
    __shared__ __align__(16) unsigned short sB[2][256 * 64];

    const int tid  = threadIdx.x;
    const int wave = tid >> 6;
    const int lane = tid & 63;
    const int wm = wave & 1;
    const int wn = wave >> 1;

    const int bid = blockIdx.x;
    const int swz = (bid & 7) * 64 + (bid >> 3);
    const int m0 = (swz >> 3) * 256;
    const int n0 = (swz & 7) * 128;

    unsigned short* __restrict__ H =
        (m0 < 8192) ? Hlo : (Hhi - (size_t)8192 * DM);

    const int rA = lane & 15;
    const int qq = lane >> 4;
    const int r7 = rA & 7;
    const int swq   = ((qq ^ (r7 & 3)) << 4);
    const int k0off = ((rA >> 2) & 1) << 6;
    const int k1off = k0off ^ 64;
    const int ldsA_base = (wm * 64 + rA) * 128 + swq;
    const int ldsB_base = (wn * 16 + rA) * 128 + swq;

    const int trow = tid >> 3;
    const int tsw  = (((tid & 7) ^ (trow & 7)) << 4);
    const char* srcA  = (const char*)X   + (size_t)(m0 + trow) * 2048 + tsw;
    const char* srcBg = (const char*)WgT + (size_t)(n0 + trow) * 2048 + tsw;
    const char* srcBo = (const char*)WoT + (size_t)(n0 + trow) * 2048 + tsw;
    char* dA = (char*)&sA[0][0] + tid * 16;
    char* dB = (char*)&sB[0][0] + tid * 16;

#define STA1(b, kt, r)  async_load16(srcA  + (kt) * 128 + (r) * 131072, dA + (b) * 32768 + (r) * 8192)
#define STBG1(b, kt, r) async_load16(srcBg + (kt) * 128 + (r) * 131072, dB + (b) * 32768 + (r) * 8192)
#define STBO1(b, kt, r) async_load16(srcBo + (kt) * 128 + (r) * 131072, dB + (b) * 32768 + (2 + (r)) * 8192)
#define LDA1(dst, bb, h, il, kof) dst = *(const bf16x8*)((const char*)sA + (bb) * 32768 + ldsA_base + (h) * 16384 + (il) * 2048 + (kof))
#define LDB1(dst, bb, mat, j, kof) dst = *(const bf16x8*)((const char*)sB + (bb) * 32768 + ldsB_base + (mat) * 16384 + (j) * 8192 + (kof))

    f32x4 aG[2][4][2], aO[2][4][2];
    bf16x8 fa[4][2], fbg[2][2], fbo[2][2];

    STA1(0, 0, 0); STA1(0, 0, 1); STA1(0, 0, 2); STA1(0, 0, 3);
    STBG1(0, 0, 0); STBG1(0, 0, 1); STBO1(0, 0, 0); STBO1(0, 0, 1);
    STA1(1, 1, 0); STA1(1, 1, 1); STBG1(1, 1, 0); STBO1(1, 1, 0);

#pragma unroll
    for (int h = 0; h < 2; ++h)
#pragma unroll
        for (int il = 0; il < 4; ++il)
#pragma unroll
            for (int jl = 0; jl < 2; ++jl) {
                aG[h][il][jl] = (f32x4){0.f, 0.f, 0.f, 0.f};
                aO[h][il][jl] = (f32x4){0.f, 0.f, 0.f, 0.f};
            }

    asm volatile("s_waitcnt vmcnt(4)" ::: "memory");
    __builtin_amdgcn_s_barrier();

#define MM1(H_) do { \
    _Pragma("unroll") \
    for (int kk = 0; kk < 2; ++kk) \
        _Pragma("unroll") \
        for (int il = 0; il < 4; ++il) \
            _Pragma("unroll") \
            for (int jl = 0; jl < 2; ++jl) { \
                aG[H_][il][jl] = __builtin_amdgcn_mfma_f32_16x16x32_bf16(fa[il][kk], fbg[jl][kk], aG[H_][il][jl], 0, 0, 0); \
                aO[H_][il][jl] = __builtin_amdgcn_mfma_f32_16x16x32_bf16(fa[il][kk], fbo[jl][kk], aO[H_][il][jl], 0, 0, 0); \
            } } while (0)

#define TILE1(kt, b, nb) do { \
    _Pragma("unroll") \
    for (int il = 0; il < 4; ++il) { LDA1(fa[il][0], b, 0, il, k0off); LDA1(fa[il][1], b, 0, il, k1off); } \
    _Pragma("unroll") \
    for (int jl = 0; jl < 2; ++jl) { \
        LDB1(fbg[jl][0], b, 0, jl, k0off); LDB1(fbg[jl][1], b, 0, jl, k1off); \
        LDB1(fbo[jl][0], b, 1, jl, k0off); LDB1(fbo[jl][1], b, 1, jl, k1off); } \
    if ((kt) < 15) { STA1(nb, (kt) + 1, 2); STA1(nb, (kt) + 1, 3); STBG1(nb, (kt) + 1, 1); STBO1(nb, (kt) + 1, 1); } \
    asm volatile("s_waitcnt lgkmcnt(0)" ::: "memory"); \
    __builtin_amdgcn_sched_barrier(0); \
    __builtin_amdgcn_s_setprio(1); MM1(0); __builtin_amdgcn_s_setprio(0); \
    __builtin_amdgcn_s_barrier(); \
    _Pragma("unroll") \
    for (int il = 0; il < 4; ++il) { LDA1(fa[il][0], b, 1, il, k0off); LDA1(fa[il][1], b, 1, il, k1off); } \
    if ((kt) < 14) { STA1(b, (kt) + 2, 0); STA1(b, (kt) + 2, 1); STBG1(b, (kt) + 2, 0); STBO1(b, (kt) + 2, 0); } \
    asm volatile("s_waitcnt lgkmcnt(0)" ::: "memory"); \
    __builtin_amdgcn_sched_barrier(0); \
    __builtin_amdgcn_s_setprio(1); MM1(1); __builtin_amdgcn_s_setprio(0); \
    if ((kt) < 14) { asm volatile("s_waitcnt vmcnt(4)" ::: "memory"); } \
    else           { asm volatile("s_waitcnt vmcnt(0)" ::: "memory"); } \
    __builtin_amdgcn_s_barrier(); \
} while (0)

#pragma unroll 1
    for (int kt2 = 0; kt2 < 16; kt2 += 2) {
        TILE1(kt2, 0, 1);
        TILE1(kt2 + 1, 1, 0);
    }
#undef TILE1
#undef MM1
#undef STA1
#undef STBG1
#undef STBO1
#undef LDA1
#undef LDB1

    const int colL = lane & 15;
    const int rowQ = (lane >> 4) * 4;
#pragma unroll
    for (int jl = 0; jl < 2; ++jl) {
        const int n = n0 + wn * 16 + jl * 64 + colL;
        const float bgv = bproj[n];
        const float bov = bproj[2048 + n];
#pragma unroll
        for (int h = 0; h < 2; ++h)
#pragma unroll
            for (int il = 0; il < 4; ++il) {
                const int mbase = m0 + wm * 64 + h * 128 + il * 16 + rowQ;
#pragma unroll
                for (int r = 0; r < 4; ++r) {
                    const float g = aG[h][il][jl][r] + bgv;
                    const float o = aO[h][il][jl][r] + bov;
                    const float hv = g * (1.0f / (1.0f + __expf(-o)));
                    H[(size_t)(mbase + r) * DM + n] = f2bf(hv);
                }
            }
    }
}

// -------- GEMM2: Out = H @ WoutT^T + b; CLONE of gemm1 structure -------------
// BM=256, BN=256 (4 x 64-col j-panels), 8 waves (2M x 4N), LDS 128 KiB.
// Per wave per K-tile: 24 ds_read_b128 + 12 staged loads + 64 MFMA (=gemm1).
__global__ __launch_bounds__(512)
void gemm2(const unsigned short* __restrict__ Hlo,
           const unsigned short* __restrict__ Hhi,
           const unsigned short* __restrict__ Bt,
           const float* __restrict__ bout,
           float* __restrict__ Out,
           int row_base) {
    __shared__ __align__(16) unsigned short sA[2][256 * 64];
    __shared__ __align__(16) unsigned short sB[2][256 * 64];

    const int tid  = threadIdx.x;
    const int wave = tid >> 6;
    const int lane = tid & 63;
    const int wm = wave & 1;       // 2 M-waves x (2 x 64 rows)
    const int wn = wave >> 1;      // 4 N-waves x (4 x 16 cols)

    const int bid = blockIdx.x;
    const int q8  = (int)gridDim.x >> 3;      // 256 or 128 blocks (%8==0)
    const int swz = (bid & 7) * q8 + (bid >> 3);
    const int m0 = row_base + (swz >> 2) * 256;
    const int n0 = (swz & 3) * 256;

    const unsigned short* __restrict__ A =
        (m0 < 8192) ? (Hlo + (size_t)m0 * DM) : (Hhi + (size_t)(m0 - 8192) * DM);

    const int rA = lane & 15;
    const int qq = lane >> 4;
    const int r7 = rA & 7;
    const int swq   = ((qq ^ (r7 & 3)) << 4);
    const int k0off = ((rA >> 2) & 1) << 6;
    const int k1off = k0off ^ 64;
    const int ldsA_base = (wm * 64 + rA) * 128 + swq;
    const int ldsB_base = (wn * 16 + rA) * 128 + swq;

    const int trow = tid >> 3;                // 0..63: region = 64 rows
    const int tsw  = (((tid & 7) ^ (trow & 7)) << 4);
    const char* srcA = (const char*)A  + (size_t)trow * 2048 + tsw;
    const char* srcB = (const char*)Bt + (size_t)(n0 + trow) * 2048 + tsw;
    char* dA = (char*)&sA[0][0] + tid * 16;
    char* dB = (char*)&sB[0][0] + tid * 16;

#define STA2(b, kt, r) async_load16(srcA + (kt) * 128 + (r) * 131072, dA + (b) * 32768 + (r) * 8192)
#define STB2(b, kt, r) async_load16(srcB + (kt) * 128 + (r) * 131072, dB + (b) * 32768 + (r) * 8192)
#define LDA2(dst, bb, h, il, kof) dst = *(const bf16x8*)((const char*)sA + (bb) * 32768 + ldsA_base + (h) * 16384 + (il) * 2048 + (kof))
#define LDB2(dst, bb, jl, kof)    dst = *(const bf16x8*)((const char*)sB + (bb) * 32768 + ldsB_base + (jl) * 8192 + (kof))

    f32x4 acc[2][4][4];
    bf16x8 fa[4][2], fb[4][2];

    // prologue: tile0 complete (8 regions), then tile1's {A0,A1,B0,B1}
    STA2(0, 0, 0); STA2(0, 0, 1); STA2(0, 0, 2); STA2(0, 0, 3);
    STB2(0, 0, 0); STB2(0, 0, 1); STB2(0, 0, 2); STB2(0, 0, 3);
    STA2(1, 1, 0); STA2(1, 1, 1); STB2(1, 1, 0); STB2(1, 1, 1);

#pragma unroll
    for (int h = 0; h < 2; ++h)
#pragma unroll
        for (int il = 0; il < 4; ++il)
#pragma unroll
            for (int jl = 0; jl < 4; ++jl)
                acc[h][il][jl] = (f32x4){0.f, 0.f, 0.f, 0.f};

    asm volatile("s_waitcnt vmcnt(4)" ::: "memory");   // tile0 landed
    __builtin_amdgcn_s_barrier();

#define MM2(H_) do { \
    _Pragma("unroll") \
    for (int kk = 0; kk < 2; ++kk) \
        _Pragma("unroll") \
        for (int il = 0; il < 4; ++il) \
            _Pragma("unroll") \
            for (int jl = 0; jl < 4; ++jl) \
                acc[H_][il][jl] = __builtin_amdgcn_mfma_f32_16x16x32_bf16(fa[il][kk], fb[jl][kk], acc[H_][il][jl], 0, 0, 0); \
    } while (0)

#define TILE2(kt, b, nb) do { \
    /* p0: read A-h0(8) + ALL B(8); stage kt+1 {A2,A3,B2,B3} -> nb */ \
    _Pragma("unroll") \
    for (int il = 0; il < 4; ++il) { LDA2(fa[il][0], b, 0, il, k0off); LDA2(fa[il][1], b, 0, il, k1off); } \
    _Pragma("unroll") \
    for (int jl = 0; jl < 4; ++jl) { LDB2(fb[jl][0], b, jl, k0off); LDB2(fb[jl][1], b, jl, k1off); } \
    if ((kt) < 15) { STA2(nb, (kt) + 1, 2); STA2(nb, (kt) + 1, 3); STB2(nb, (kt) + 1, 2); STB2(nb, (kt) + 1, 3); } \
    asm volatile("s_waitcnt lgkmcnt(0)" ::: "memory"); \
    __builtin_amdgcn_sched_barrier(0); \
    __builtin_amdgcn_s_setprio(1); MM2(0); __builtin_amdgcn_s_setprio(0); \
    __builtin_amdgcn_s_barrier(); \
    /* p1: read A-h1(8); stage kt+2 {A0,A1,B0,B1} -> b */ \
    _Pragma("unroll") \
    for (int il = 0; il < 4; ++il) { LDA2(fa[il][0], b, 1, il, k0off); LDA2(fa[il][1], b, 1, il, k1off); } \
    if ((kt) < 14) { STA2(b, (kt) + 2, 0); STA2(b, (kt) + 2, 1); STB2(b, (kt) + 2, 0); STB2(b, (kt) + 2, 1); } \
    asm volatile("s_waitcnt lgkmcnt(0)" ::: "memory"); \
    __builtin_amdgcn_sched_barrier(0); \
    __builtin_amdgcn_s_setprio(1); MM2(1); __builtin_amdgcn_s_setprio(0); \
    if ((kt) < 14) { asm volatile("s_waitcnt vmcnt(4)" ::: "memory"); } \
    else           { asm volatile("s_waitcnt vmcnt(0)" ::: "memory"); } \
    __builtin_amdgcn_s_barrier(); \
} while (0)

#pragma unroll 1
    for (int kt2 = 0; kt2 < 16; kt2 += 2) {
        TILE2(kt2, 0, 1);
        TILE2(kt2 + 1, 1, 0);
    }
#undef TILE2
#undef MM2
#undef STA2
#undef STB2
#undef LDA2
#undef LDB2

    const int colL = lane & 15;
    const int rowQ = (lane >> 4) * 4;
#pragma unroll
    for (int jl = 0; jl < 4; ++jl) {
        const int n = n0 + wn * 16 + jl * 64 + colL;
        const float bv = bout[n];
#pragma unroll
        for (int h = 0; h < 2; ++h)
#pragma unroll
            for (int il = 0; il < 4; ++il) {
                const int mbase = m0 + wm * 64 + h * 128 + il * 16 + rowQ;
#pragma unroll
                for (int r = 0; r < 4; ++r)
                    Out[(size_t)(mbase + r) * DM + n] = acc[h][il][jl][r] + bv;
            }
    }
}

extern "C" void kernel_launch(void* const* d_in, const int* in_sizes, int n_in,
                              void* d_out, int out_size, void* d_ws, size_t ws_size,
                              hipStream_t stream) {
    const float* x     = (const float*)d_in[0];   // [4,4096,1024] fp32
    const float* Wproj = (const float*)d_in[1];   // [1024,3072]   fp32
    const float* bproj = (const float*)d_in[2];   // [3072]        fp32
    const float* Wout  = (const float*)d_in[3];   // [1024,1024]   fp32
    const float* bout  = (const float*)d_in[4];   // [1024]        fp32
    float* out = (float*)d_out;                   // [4,4096,1024] fp32 (64 MB)

    unsigned short* Xb  = (unsigned short*)d_out; // shorts [0,16M): Xbf16 (phases 1-3)
    unsigned short* WgT   = (unsigned short*)d_ws;
    unsigned short* WoT   = WgT + MEG;
    unsigned short* WoutT = WgT + 2 * MEG;
    unsigned short* Hws   = WgT + 3 * MEG;

    const bool big_ws = ws_size >= (size_t)19 * MEG * 2;

    unsigned short* Hlo = big_ws ? Hws : ((unsigned short*)d_out + 16 * MEG);
    unsigned short* Hhi = big_ws ? (Hws + (size_t)8192 * DM) : Hws;

    // 1) Xbf16 (d_out lo) <- fp32 x
    conv_x<<<(MTOT * DM) / (256 * 8), 256, 0, stream>>>(x, Xb);

    // 2) transposed bf16 weight panels -> ws
    transpose_w<<<dim3(32, 32, 3), dim3(32, 8, 1), 0, stream>>>(Wproj, Wout, WgT);

    // 3) H = (X@Wg + bg) * sigmoid(X@Wo + bo), stored split across Hlo/Hhi
    gemm1_fused<<<512, 512, 0, stream>>>(Xb, WgT, WoT, bproj, Hlo, Hhi);

    // 4) out = H @ Wout + b_out (256x256 tiles, gemm1-clone structure)
    if (big_ws) {
        gemm2<<<256, 512, 0, stream>>>(Hlo, Hhi, WoutT, bout, out, 0);
    } else {
        // lo half first (reads d_out-hi H, writes d_out-lo out: disjoint),
        // then hi half (reads only ws, overwrites the now-dead H-lo region)
        gemm2<<<128, 512, 0, stream>>>(Hlo, Hhi, WoutT, bout, out, 0);
        gemm2<<<128, 512, 0, stream>>>(Hlo, Hhi, WoutT, bout, out, 8192);
    }
}

// Round 9
// 231.055 us; speedup vs baseline: 1.0338x; 1.0338x over previous
//
#include <hip/hip_runtime.h>
#include <hip/hip_bf16.h>

// B=4, L=4096, D=1024; M = B*L = 16384. ALL I/O IS FP32.
// Live path: h = (x@Wp[:,0:D]) * sigmoid(x@Wp[:,2D:3D]); out = h@W_out + b_out
// Internals: bf16 MFMA, fp32 accumulation.
//
// Round-9 (consolidation under measured +/-20% cross-round noise):
//  - prep: conv_x + transpose_w MERGED into one launch (one fewer boundary).
//  - gemm1: EXACT round-4 kernel (best verified 73.7us; R8's 90us was
//    byte-identical code -> chip-state noise).
//  - gemm2 big-ws: round-8 256x256 gemm1-clone, 256 blocks = one
//    full-machine round.
//  - gemm2 small-ws: round-6 128x128 / 256-thr / 2-blocks-per-CU kernel at
//    512 blocks per half (FULL machine; fixes R8's 2x128 half-machine path).
//
// 2-phase K-tile (both gemms), 1 barrier per phase:
//   p0: reads + stage-next -> lgkmcnt(0) wall -> MFMA -> barrier
//   p1: reads + stage-next+1 -> lgkmcnt(0) wall -> MFMA -> vmcnt(4) -> barrier
// T2 LDS XOR swizzle (slot^=row&7 on 128B rows; linear LDS dest +
// inverse-swizzled global source), T5 setprio, T1 XCD block swizzle.
//
// Memory plan (ws_size-adaptive, branch constant across calls => graph-safe):
//   ws shorts [0,3M)   : WgT | WoT | WoutT bf16 panels (6 MB)
//   BIG ws (>=38 MB)   : H (16M shorts) entirely at ws+3M; single gemm2 launch.
//   SMALL ws           : H rows 0..8191 -> d_out shorts [16M,24M);
//                        H rows 8192..  -> ws+3M; two sequential gemm2 halves.
//   d_out shorts [0,16M): Xbf16 during prep/gemm1, then fp32 out rows 0..8191.

#define MTOT 16384
#define DM   1024
#define MEG  (1024 * 1024)

typedef __bf16 bf16x8 __attribute__((ext_vector_type(8)));
typedef float  f32x4  __attribute__((ext_vector_type(4)));

#define AS1 __attribute__((address_space(1)))
#define AS3 __attribute__((address_space(3)))

static __device__ __forceinline__ void async_load16(const void* g, void* l) {
    __builtin_amdgcn_global_load_lds((const AS1 void*)g, (AS3 void*)l, 16, 0, 0);
}

static __device__ __forceinline__ unsigned short f2bf(float f) {
    __hip_bfloat16 h = __float2bfloat16(f);
    return *(unsigned short*)&h;
}

// ------------- prep: conv_x (blocks 0..8191) + transpose_w (8192..11263) -----
__global__ __launch_bounds__(256)
void prep(const float* __restrict__ x, const float* __restrict__ Wproj,
          const float* __restrict__ Wout,
          unsigned short* __restrict__ Xb, unsigned short* __restrict__ Wdst) {
    __shared__ unsigned short t[32][33];
    const int bid = blockIdx.x;
    const int tid = threadIdx.x;
    if (bid < 8192) {
        // conv: x fp32 -> Xbf16, 8 elems/thread, fully coalesced
        const size_t i = ((size_t)bid * 256 + tid) * 8;
        const f32x4 a = *(const f32x4*)(x + i);
        const f32x4 b = *(const f32x4*)(x + i + 4);
        __align__(16) unsigned short o[8];
        o[0] = f2bf(a[0]); o[1] = f2bf(a[1]); o[2] = f2bf(a[2]); o[3] = f2bf(a[3]);
        o[4] = f2bf(b[0]); o[5] = f2bf(b[1]); o[6] = f2bf(b[2]); o[7] = f2bf(b[3]);
        *(uint4*)(Xb + i) = *(const uint4*)o;
        return;
    }
    // transpose: dst[n][k] = bf16(src[k][coff+n])
    const int bid2 = bid - 8192;          // 0..3071
    const int z  = bid2 >> 10;            // 0..2
    const int rem = bid2 & 1023;
    const int k0 = (rem & 31) * 32;
    const int n0 = (rem >> 5) * 32;
    const float* src;
    unsigned short* dst;
    int ld, coff;
    if (z == 0)      { src = Wproj; ld = 3072; coff = 0;    dst = Wdst; }
    else if (z == 1) { src = Wproj; ld = 3072; coff = 2048; dst = Wdst + MEG; }
    else             { src = Wout;  ld = 1024; coff = 0;    dst = Wdst + 2 * MEG; }
    const int tx = tid & 31, ty = tid >> 5;   // 32 x 8
    for (int i = ty; i < 32; i += 8)
        t[i][tx] = f2bf(src[(size_t)(k0 + i) * ld + coff + n0 + tx]);
    __syncthreads();
    for (int i = ty; i < 32; i += 8)
        dst[(size_t)(n0 + i) * DM + k0 + tx] = t[tx][i];
}

// ---------- GEMM1 fused: H = (X@Wg + bg) * sigmoid(X@Wo + bo) ---------------
// EXACT round-4 kernel. 512 thr / 8 waves (2M x 4N); BM=256, BN=128(x2 mats).
__global__ __launch_bounds__(512)
void gemm1_fused(const unsigned short* __restrict__ X,
                 const unsigned short* __restrict__ WgT,
                 const unsigned short* __restrict__ WoT,
                 const float* __restrict__ bproj,
                 unsigned short* __restrict__ Hlo,
                 unsigned short* __restrict__ Hhi) {
    __shared__ __align__(16) unsigned short sA[2][256 * 64];
    __shared__ __align__(16) unsigned short sB[2][256 * 64];

    const int tid  = threadIdx.x;
    const int wave = tid >> 6;
    const int lane = tid & 63;
    const int wm = wave & 1;
    const int wn = wave >> 1;

    const int bid = blockIdx.x;
    const int swz = (bid & 7) * 64 + (bid >> 3);
    const int m0 = (swz >> 3) * 256;
    const int n0 = (swz & 7) * 128;

    unsigned short* __restrict__ H =
        (m0 < 8192) ? Hlo : (Hhi - (size_t)8192 * DM);

    const int rA = lane & 15;
    const int qq = lane >> 4;
    const int r7 = rA & 7;
    const int swq   = ((qq ^ (r7 & 3)) << 4);
    const int k0off = ((rA >> 2) & 1) << 6;
    const int k1off = k0off ^ 64;
    const int ldsA_base = (wm * 64 + rA) * 128 + swq;
    const int ldsB_base = (wn * 16 + rA) * 128 + swq;

    const int trow = tid >> 3;
    const int tsw  = (((tid & 7) ^ (trow & 7)) << 4);
    const char* srcA  = (const char*)X   + (size_t)(m0 + trow) * 2048 + tsw;
    const char* srcBg = (const char*)WgT + (size_t)(n0 + trow) * 2048 + tsw;
    const char* srcBo = (const char*)WoT + (size_t)(n0 + trow) * 2048 + tsw;
    char* dA = (char*)&sA[0][0] + tid * 16;
    char* dB = (char*)&sB[0][0] + tid * 16;

#define STA1(b, kt, r)  async_load16(srcA  + (kt) * 128 + (r) * 131072, dA + (b) * 32768 + (r) * 8192)
#define STBG1(b, kt, r) async_load16(srcBg + (kt) * 128 + (r) * 131072, dB + (b) * 32768 + (r) * 8192)
#define STBO1(b, kt, r) async_load16(srcBo + (kt) * 128 + (r) * 131072, dB + (b) * 32768 + (2 + (r)) * 8192)
#define LDA1(dst, bb, h, il, kof) dst = *(const bf16x8*)((const char*)sA + (bb) * 32768 + ldsA_base + (h) * 16384 + (il) * 2048 + (kof))
#define LDB1(dst, bb, mat, j, kof) dst = *(const bf16x8*)((const char*)sB + (bb) * 32768 + ldsB_base + (mat) * 16384 + (j) * 8192 + (kof))

    f32x4 aG[2][4][2], aO[2][4][2];
    bf16x8 fa[4][2], fbg[2][2], fbo[2][2];

    STA1(0, 0, 0); STA1(0, 0, 1); STA1(0, 0, 2); STA1(0, 0, 3);
    STBG1(0, 0, 0); STBG1(0, 0, 1); STBO1(0, 0, 0); STBO1(0, 0, 1);
    STA1(1, 1, 0); STA1(1, 1, 1); STBG1(1, 1, 0); STBO1(1, 1, 0);

#pragma unroll
    for (int h = 0; h < 2; ++h)
#pragma unroll
        for (int il = 0; il < 4; ++il)
#pragma unroll
            for (int jl = 0; jl < 2; ++jl) {
                aG[h][il][jl] = (f32x4){0.f, 0.f, 0.f, 0.f};
                aO[h][il][jl] = (f32x4){0.f, 0.f, 0.f, 0.f};
            }

    asm volatile("s_waitcnt vmcnt(4)" ::: "memory");
    __builtin_amdgcn_s_barrier();

#define MM1(H_) do { \
    _Pragma("unroll") \
    for (int kk = 0; kk < 2; ++kk) \
        _Pragma("unroll") \
        for (int il = 0; il < 4; ++il) \
            _Pragma("unroll") \
            for (int jl = 0; jl < 2; ++jl) { \
                aG[H_][il][jl] = __builtin_amdgcn_mfma_f32_16x16x32_bf16(fa[il][kk], fbg[jl][kk], aG[H_][il][jl], 0, 0, 0); \
                aO[H_][il][jl] = __builtin_amdgcn_mfma_f32_16x16x32_bf16(fa[il][kk], fbo[jl][kk], aO[H_][il][jl], 0, 0, 0); \
            } } while (0)

#define TILE1(kt, b, nb) do { \
    _Pragma("unroll") \
    for (int il = 0; il < 4; ++il) { LDA1(fa[il][0], b, 0, il, k0off); LDA1(fa[il][1], b, 0, il, k1off); } \
    _Pragma("unroll") \
    for (int jl = 0; jl < 2; ++jl) { \
        LDB1(fbg[jl][0], b, 0, jl, k0off); LDB1(fbg[jl][1], b, 0, jl, k1off); \
        LDB1(fbo[jl][0], b, 1, jl, k0off); LDB1(fbo[jl][1], b, 1, jl, k1off); } \
    if ((kt) < 15) { STA1(nb, (kt) + 1, 2); STA1(nb, (kt) + 1, 3); STBG1(nb, (kt) + 1, 1); STBO1(nb, (kt) + 1, 1); } \
    asm volatile("s_waitcnt lgkmcnt(0)" ::: "memory"); \
    __builtin_amdgcn_sched_barrier(0); \
    __builtin_amdgcn_s_setprio(1); MM1(0); __builtin_amdgcn_s_setprio(0); \
    __builtin_amdgcn_s_barrier(); \
    _Pragma("unroll") \
    for (int il = 0; il < 4; ++il) { LDA1(fa[il][0], b, 1, il, k0off); LDA1(fa[il][1], b, 1, il, k1off); } \
    if ((kt) < 14) { STA1(b, (kt) + 2, 0); STA1(b, (kt) + 2, 1); STBG1(b, (kt) + 2, 0); STBO1(b, (kt) + 2, 0); } \
    asm volatile("s_waitcnt lgkmcnt(0)" ::: "memory"); \
    __builtin_amdgcn_sched_barrier(0); \
    __builtin_amdgcn_s_setprio(1); MM1(1); __builtin_amdgcn_s_setprio(0); \
    if ((kt) < 14) { asm volatile("s_waitcnt vmcnt(4)" ::: "memory"); } \
    else           { asm volatile("s_waitcnt vmcnt(0)" ::: "memory"); } \
    __builtin_amdgcn_s_barrier(); \
} while (0)

#pragma unroll 1
    for (int kt2 = 0; kt2 < 16; kt2 += 2) {
        TILE1(kt2, 0, 1);
        TILE1(kt2 + 1, 1, 0);
    }
#undef TILE1
#undef MM1
#undef STA1
#undef STBG1
#undef STBO1
#undef LDA1
#undef LDB1

    const int colL = lane & 15;
    const int rowQ = (lane >> 4) * 4;
#pragma unroll
    for (int jl = 0; jl < 2; ++jl) {
        const int n = n0 + wn * 16 + jl * 64 + colL;
        const float bgv = bproj[n];
        const float bov = bproj[2048 + n];
#pragma unroll
        for (int h = 0; h < 2; ++h)
#pragma unroll
            for (int il = 0; il < 4; ++il) {
                const int mbase = m0 + wm * 64 + h * 128 + il * 16 + rowQ;
#pragma unroll
                for (int r = 0; r < 4; ++r) {
                    const float g = aG[h][il][jl][r] + bgv;
                    const float o = aO[h][il][jl][r] + bov;
                    const float hv = g * (1.0f / (1.0f + __expf(-o)));
                    H[(size_t)(mbase + r) * DM + n] = f2bf(hv);
                }
            }
    }
}

// -------- GEMM2 (big-ws): 256x256 gemm1-clone, 256 blocks = 1 full round -----
__global__ __launch_bounds__(512)
void gemm2_big(const unsigned short* __restrict__ Hlo,
               const unsigned short* __restrict__ Hhi,
               const unsigned short* __restrict__ Bt,
               const float* __restrict__ bout,
               float* __restrict__ Out) {
    __shared__ __align__(16) unsigned short sA[2][256 * 64];
    __shared__ __align__(16) unsigned short sB[2][256 * 64];

    const int tid  = threadIdx.x;
    const int wave = tid >> 6;
    const int lane = tid & 63;
    const int wm = wave & 1;
    const int wn = wave >> 1;

    const int bid = blockIdx.x;
    const int swz = (bid & 7) * 32 + (bid >> 3);   // 256 blocks
    const int m0 = (swz >> 2) * 256;
    const int n0 = (swz & 3) * 256;

    const unsigned short* __restrict__ A =
        (m0 < 8192) ? (Hlo + (size_t)m0 * DM) : (Hhi + (size_t)(m0 - 8192) * DM);

    const int rA = lane & 15;
    const int qq = lane >> 4;
    const int r7 = rA & 7;
    const int swq   = ((qq ^ (r7 & 3)) << 4);
    const int k0off = ((rA >> 2) & 1) << 6;
    const int k1off = k0off ^ 64;
    const int ldsA_base = (wm * 64 + rA) * 128 + swq;
    const int ldsB_base = (wn * 16 + rA) * 128 + swq;

    const int trow = tid >> 3;
    const int tsw  = (((tid & 7) ^ (trow & 7)) << 4);
    const char* srcA = (const char*)A  + (size_t)trow * 2048 + tsw;
    const char* srcB = (const char*)Bt + (size_t)(n0 + trow) * 2048 + tsw;
    char* dA = (char*)&sA[0][0] + tid * 16;
    char* dB = (char*)&sB[0][0] + tid * 16;

#define STA2(b, kt, r) async_load16(srcA + (kt) * 128 + (r) * 131072, dA + (b) * 32768 + (r) * 8192)
#define STB2(b, kt, r) async_load16(srcB + (kt) * 128 + (r) * 131072, dB + (b) * 32768 + (r) * 8192)
#define LDA2(dst, bb, h, il, kof) dst = *(const bf16x8*)((const char*)sA + (bb) * 32768 + ldsA_base + (h) * 16384 + (il) * 2048 + (kof))
#define LDB2(dst, bb, jl, kof)    dst = *(const bf16x8*)((const char*)sB + (bb) * 32768 + ldsB_base + (jl) * 8192 + (kof))

    f32x4 acc[2][4][4];
    bf16x8 fa[4][2], fb[4][2];

    STA2(0, 0, 0); STA2(0, 0, 1); STA2(0, 0, 2); STA2(0, 0, 3);
    STB2(0, 0, 0); STB2(0, 0, 1); STB2(0, 0, 2); STB2(0, 0, 3);
    STA2(1, 1, 0); STA2(1, 1, 1); STB2(1, 1, 0); STB2(1, 1, 1);

#pragma unroll
    for (int h = 0; h < 2; ++h)
#pragma unroll
        for (int il = 0; il < 4; ++il)
#pragma unroll
            for (int jl = 0; jl < 4; ++jl)
                acc[h][il][jl] = (f32x4){0.f, 0.f, 0.f, 0.f};

    asm volatile("s_waitcnt vmcnt(4)" ::: "memory");
    __builtin_amdgcn_s_barrier();

#define MM2(H_) do { \
    _Pragma("unroll") \
    for (int kk = 0; kk < 2; ++kk) \
        _Pragma("unroll") \
        for (int il = 0; il < 4; ++il) \
            _Pragma("unroll") \
            for (int jl = 0; jl < 4; ++jl) \
                acc[H_][il][jl] = __builtin_amdgcn_mfma_f32_16x16x32_bf16(fa[il][kk], fb[jl][kk], acc[H_][il][jl], 0, 0, 0); \
    } while (0)

#define TILE2(kt, b, nb) do { \
    _Pragma("unroll") \
    for (int il = 0; il < 4; ++il) { LDA2(fa[il][0], b, 0, il, k0off); LDA2(fa[il][1], b, 0, il, k1off); } \
    _Pragma("unroll") \
    for (int jl = 0; jl < 4; ++jl) { LDB2(fb[jl][0], b, jl, k0off); LDB2(fb[jl][1], b, jl, k1off); } \
    if ((kt) < 15) { STA2(nb, (kt) + 1, 2); STA2(nb, (kt) + 1, 3); STB2(nb, (kt) + 1, 2); STB2(nb, (kt) + 1, 3); } \
    asm volatile("s_waitcnt lgkmcnt(0)" ::: "memory"); \
    __builtin_amdgcn_sched_barrier(0); \
    __builtin_amdgcn_s_setprio(1); MM2(0); __builtin_amdgcn_s_setprio(0); \
    __builtin_amdgcn_s_barrier(); \
    _Pragma("unroll") \
    for (int il = 0; il < 4; ++il) { LDA2(fa[il][0], b, 1, il, k0off); LDA2(fa[il][1], b, 1, il, k1off); } \
    if ((kt) < 14) { STA2(b, (kt) + 2, 0); STA2(b, (kt) + 2, 1); STB2(b, (kt) + 2, 0); STB2(b, (kt) + 2, 1); } \
    asm volatile("s_waitcnt lgkmcnt(0)" ::: "memory"); \
    __builtin_amdgcn_sched_barrier(0); \
    __builtin_amdgcn_s_setprio(1); MM2(1); __builtin_amdgcn_s_setprio(0); \
    if ((kt) < 14) { asm volatile("s_waitcnt vmcnt(4)" ::: "memory"); } \
    else           { asm volatile("s_waitcnt vmcnt(0)" ::: "memory"); } \
    __builtin_amdgcn_s_barrier(); \
} while (0)

#pragma unroll 1
    for (int kt2 = 0; kt2 < 16; kt2 += 2) {
        TILE2(kt2, 0, 1);
        TILE2(kt2 + 1, 1, 0);
    }
#undef TILE2
#undef MM2
#undef STA2
#undef STB2
#undef LDA2
#undef LDB2

    const int colL = lane & 15;
    const int rowQ = (lane >> 4) * 4;
#pragma unroll
    for (int jl = 0; jl < 4; ++jl) {
        const int n = n0 + wn * 16 + jl * 64 + colL;
        const float bv = bout[n];
#pragma unroll
        for (int h = 0; h < 2; ++h)
#pragma unroll
            for (int il = 0; il < 4; ++il) {
                const int mbase = m0 + wm * 64 + h * 128 + il * 16 + rowQ;
#pragma unroll
                for (int r = 0; r < 4; ++r)
                    Out[(size_t)(mbase + r) * DM + n] = acc[h][il][jl][r] + bv;
            }
    }
}

// -------- GEMM2 (small-ws): 128x128, 256 thr, 2 blocks/CU, 512 blocks/half ---
__global__ __launch_bounds__(256)
void gemm2_small(const unsigned short* __restrict__ Hlo,
                 const unsigned short* __restrict__ Hhi,
                 const unsigned short* __restrict__ Bt,
                 const float* __restrict__ bout,
                 float* __restrict__ Out,
                 int row_base) {
    __shared__ __align__(16) unsigned short sA[2][128 * 64];
    __shared__ __align__(16) unsigned short sB[2][128 * 64];

    const int tid  = threadIdx.x;
    const int wave = tid >> 6;
    const int lane = tid & 63;
    const int wm = wave & 1;
    const int wn = wave >> 1;

    const int bid = blockIdx.x;
    const int q8  = (int)gridDim.x >> 3;      // 512 blocks -> 64
    const int swz = (bid & 7) * q8 + (bid >> 3);
    const int m0 = row_base + (swz >> 3) * 128;
    const int n0 = (swz & 7) * 128;

    const unsigned short* __restrict__ A =
        (m0 < 8192) ? (Hlo + (size_t)m0 * DM) : (Hhi + (size_t)(m0 - 8192) * DM);

    const int rA = lane & 15;
    const int qq = lane >> 4;
    const int r7 = rA & 7;
    const int swq   = ((qq ^ (r7 & 3)) << 4);
    const int k0off = ((rA >> 2) & 1) << 6;
    const int k1off = k0off ^ 64;
    const int ldsA_base = (wm * 64 + rA) * 128 + swq;
    const int ldsB_base = (wn * 64 + rA) * 128 + swq;

    const int trow = tid >> 3;                // 0..31
    const int tsw  = (((tid & 7) ^ (trow & 7)) << 4);
    const char* srcA = (const char*)A  + (size_t)trow * 2048 + tsw;
    const char* srcB = (const char*)Bt + (size_t)(n0 + trow) * 2048 + tsw;
    char* dA = (char*)&sA[0][0] + tid * 16;
    char* dB = (char*)&sB[0][0] + tid * 16;

#define STA3(b, kt, r) async_load16(srcA + (kt) * 128 + (r) * 65536, dA + (b) * 16384 + (r) * 4096)
#define STB3(b, kt, r) async_load16(srcB + (kt) * 128 + (r) * 65536, dB + (b) * 16384 + (r) * 4096)
#define LDA3(dst, bb, il, kof) dst = *(const bf16x8*)((const char*)sA + (bb) * 16384 + ldsA_base + (il) * 2048 + (kof))
#define LDB3(dst, bb, jl, kof) dst = *(const bf16x8*)((const char*)sB + (bb) * 16384 + ldsB_base + (jl) * 2048 + (kof))

    f32x4 acc[4][4];
    bf16x8 fa[4][2], fb[4][2];

    STA3(0, 0, 0); STA3(0, 0, 1); STA3(0, 0, 2); STA3(0, 0, 3);
    STB3(0, 0, 0); STB3(0, 0, 1); STB3(0, 0, 2); STB3(0, 0, 3);
    STA3(1, 1, 0); STA3(1, 1, 1); STB3(1, 1, 0); STB3(1, 1, 2);

#pragma unroll
    for (int il = 0; il < 4; ++il)
#pragma unroll
        for (int j = 0; j < 4; ++j) acc[il][j] = (f32x4){0.f, 0.f, 0.f, 0.f};

    asm volatile("s_waitcnt vmcnt(4)" ::: "memory");
    __builtin_amdgcn_s_barrier();

#define MM3(JB) do { \
    _Pragma("unroll") \
    for (int kk = 0; kk < 2; ++kk) \
        _Pragma("unroll") \
        for (int il = 0; il < 4; ++il) { \
            acc[il][JB]     = __builtin_amdgcn_mfma_f32_16x16x32_bf16(fa[il][kk], fb[JB][kk],     acc[il][JB],     0, 0, 0); \
            acc[il][JB + 1] = __builtin_amdgcn_mfma_f32_16x16x32_bf16(fa[il][kk], fb[JB + 1][kk], acc[il][JB + 1], 0, 0, 0); \
        } } while (0)

#define TILE3(kt, b, nb) do { \
    _Pragma("unroll") \
    for (int il = 0; il < 4; ++il) { LDA3(fa[il][0], b, il, k0off); LDA3(fa[il][1], b, il, k1off); } \
    _Pragma("unroll") \
    for (int jl = 0; jl < 2; ++jl) { LDB3(fb[jl][0], b, jl, k0off); LDB3(fb[jl][1], b, jl, k1off); } \
    if ((kt) < 15) { STA3(nb, (kt) + 1, 2); STA3(nb, (kt) + 1, 3); STB3(nb, (kt) + 1, 1); STB3(nb, (kt) + 1, 3); } \
    asm volatile("s_waitcnt lgkmcnt(0)" ::: "memory"); \
    __builtin_amdgcn_sched_barrier(0); \
    __builtin_amdgcn_s_setprio(1); MM3(0); __builtin_amdgcn_s_setprio(0); \
    __builtin_amdgcn_s_barrier(); \
    _Pragma("unroll") \
    for (int jl = 2; jl < 4; ++jl) { LDB3(fb[jl][0], b, jl, k0off); LDB3(fb[jl][1], b, jl, k1off); } \
    if ((kt) < 14) { STA3(b, (kt) + 2, 0); STA3(b, (kt) + 2, 1); STB3(b, (kt) + 2, 0); STB3(b, (kt) + 2, 2); } \
    asm volatile("s_waitcnt lgkmcnt(0)" ::: "memory"); \
    __builtin_amdgcn_sched_barrier(0); \
    __builtin_amdgcn_s_setprio(1); MM3(2); __builtin_amdgcn_s_setprio(0); \
    if ((kt) < 14) { asm volatile("s_waitcnt vmcnt(4)" ::: "memory"); } \
    else           { asm volatile("s_waitcnt vmcnt(0)" ::: "memory"); } \
    __builtin_amdgcn_s_barrier(); \
} while (0)

#pragma unroll 1
    for (int kt2 = 0; kt2 < 16; kt2 += 2) {
        TILE3(kt2, 0, 1);
        TILE3(kt2 + 1, 1, 0);
    }
#undef TILE3
#undef MM3
#undef STA3
#undef STB3
#undef LDA3
#undef LDB3

    const int colL = lane & 15;
    const int rowQ = (lane >> 4) * 4;
#pragma unroll
    for (int jl = 0; jl < 4; ++jl) {
        const int n = n0 + wn * 64 + jl * 16 + colL;
        const float bv = bout[n];
#pragma unroll
        for (int il = 0; il < 4; ++il) {
            const int mbase = m0 + wm * 64 + il * 16 + rowQ;
#pragma unroll
            for (int r = 0; r < 4; ++r)
                Out[(size_t)(mbase + r) * DM + n] = acc[il][jl][r] + bv;
        }
    }
}

extern "C" void kernel_launch(void* const* d_in, const int* in_sizes, int n_in,
                              void* d_out, int out_size, void* d_ws, size_t ws_size,
                              hipStream_t stream) {
    const float* x     = (const float*)d_in[0];   // [4,4096,1024] fp32
    const float* Wproj = (const float*)d_in[1];   // [1024,3072]   fp32
    const float* bproj = (const float*)d_in[2];   // [3072]        fp32
    const float* Wout  = (const float*)d_in[3];   // [1024,1024]   fp32
    const float* bout  = (const float*)d_in[4];   // [1024]        fp32
    float* out = (float*)d_out;                   // [4,4096,1024] fp32 (64 MB)

    unsigned short* Xb  = (unsigned short*)d_out; // shorts [0,16M): Xbf16
    unsigned short* WgT   = (unsigned short*)d_ws;
    unsigned short* WoutT = WgT + 2 * MEG;
    unsigned short* Hws   = WgT + 3 * MEG;

    const bool big_ws = ws_size >= (size_t)19 * MEG * 2;

    unsigned short* Hlo = big_ws ? Hws : ((unsigned short*)d_out + 16 * MEG);
    unsigned short* Hhi = big_ws ? (Hws + (size_t)8192 * DM) : Hws;

    // 1) merged prep: Xbf16 <- x, and WgT|WoT|WoutT <- transposed bf16 weights
    prep<<<8192 + 3072, 256, 0, stream>>>(x, Wproj, Wout, Xb, WgT);

    // 2) H = (X@Wg + bg) * sigmoid(X@Wo + bo), stored split across Hlo/Hhi
    gemm1_fused<<<512, 512, 0, stream>>>(Xb, WgT, WgT + MEG, bproj, Hlo, Hhi);

    // 3) out = H @ Wout + b_out — full machine in both ws paths
    if (big_ws) {
        gemm2_big<<<256, 512, 0, stream>>>(Hlo, Hhi, WoutT, bout, out);
    } else {
        // lo half first (reads d_out-hi H, writes d_out-lo out: disjoint),
        // then hi half (reads only ws, overwrites the now-dead H-lo region)
        gemm2_small<<<512, 256, 0, stream>>>(Hlo, Hhi, WoutT, bout, out, 0);
        gemm2_small<<<512, 256, 0, stream>>>(Hlo, Hhi, WoutT, bout, out, 8192);
    }
}